// Round 21
// baseline (110.285 us; speedup 1.0000x reference)
//
#include <hip/hip_runtime.h>
#include <hip/hip_bf16.h>
#include <math.h>

#define IN_DIM 256
#define OUT_DIM 64
#define CHUNK_LOG2 12          // 4096 edges per scatter chunk
#define BK_LOG2 7              // 128 dsts per coarse bucket
#define MAXNB 512              // max coarse buckets (n_p <= 65536)
#define BCAP 6144              // fixed bucket capacity (mean 4096, sd 64 -> 32 sigma)
#define PERSIST 512            // 2 blocks/CU (64 KB LDS each), one residency round

typedef __attribute__((ext_vector_type(8))) short short8v;   // 8 bf16 (4 VGPRs)
typedef __attribute__((ext_vector_type(4))) float f32x4;     // MFMA acc

__device__ __forceinline__ unsigned short f2bf(float f) {
    unsigned u = __float_as_uint(f);
    unsigned r = (u + 0x7fffu + ((u >> 16) & 1u)) >> 16;     // RTNE
    return (unsigned short)r;
}

__device__ __forceinline__ float bf2f(unsigned short b) {
    return __uint_as_float(((unsigned)b) << 16);
}

__device__ __forceinline__ float edge_score(float x) {
    float e = x > 0.0f ? x : 0.01f * x;   // leaky_relu, slope 0.01
    if (e == 0.0f) e = -1000.0f;          // where(e==0, -1000, e)
    return e;
}

// async global->LDS DMA, 16B per lane; LDS dest is wave-uniform base + lane*16
__device__ __forceinline__ void gload_lds16(const void* g, void* l) {
    __builtin_amdgcn_global_load_lds(
        (const __attribute__((address_space(1))) unsigned int*)g,
        (__attribute__((address_space(3))) unsigned int*)l, 16, 0, 0);
}

// Pre-pack W_fc (256x64 f32) into MFMA B-fragments, bf16. Grid: 8 x 256.
// Block 0 additionally zeroes bres (replaces a separate memset dispatch).
__global__ __launch_bounds__(256) void prep_kernel(
    const float* __restrict__ Wfc, short8v* __restrict__ wtf,
    int* __restrict__ bres, int nb)
{
    if (blockIdx.x == 0)
        for (int j = threadIdx.x; j < nb; j += 256) bres[j] = 0;

    const int v = blockIdx.x * 256 + threadIdx.x;   // 0..2047
    const int ks = v >> 8;
    const int t = (v >> 6) & 3;
    const int lane = v & 63;
    const int lg = lane >> 4, lr = lane & 15;
    short8v b;
    #pragma unroll
    for (int j = 0; j < 8; ++j) {
        const int k = ks * 32 + lg * 8 + j;
        b[j] = (short)f2bf(Wfc[k * OUT_DIM + t * 16 + lr]);
    }
    wtf[v] = b;
}

// PERSISTENT mega kernel, 128-thread blocks (2 waves), 64 KB LDS:
// each wave owns TWO 16 KB tile buffers and cross-tile double-buffers:
//   wait vmcnt(16) -> compute buf[cur] -> stores -> issue DMA(t+2G -> buf[cur])
// The just-issued 16 DMAs are always the only ops left un-drained, so one
// full compute phase separates each buffer's DMA issue from its consumption.
// After the gemm loop, blocks grid-stride over scatter chunks.
__global__ __launch_bounds__(128) void mega_kernel(
    const float* __restrict__ h, const short8v* __restrict__ wtf,
    const float* __restrict__ Wattn, const int* __restrict__ esrc,
    const int* __restrict__ edst, unsigned short* __restrict__ z,
    float* __restrict__ s, int* __restrict__ bres, int* __restrict__ brec,
    int n_rows, int n_edges, int nb, int nchunks, int gemmtiles)
{
    __shared__ __align__(16) char hl[65536];   // 2 waves x 2 x 16 KB / scatter tables
    const int bid = blockIdx.x;
    const int tid = threadIdx.x;
    const int lane = tid & 63;
    const int wv = tid >> 6;                   // 0 or 1
    const int lg = lane >> 4;
    const int lr = lane & 15;
    const int G = gridDim.x;

    // ---- gemm constants: loaded once, amortized over all tiles ----
    short8v Bf[8][4];
    #pragma unroll
    for (int ks = 0; ks < 8; ++ks)
        #pragma unroll
        for (int t = 0; t < 4; ++t)
            Bf[ks][t] = wtf[(ks * 4 + t) * 64 + lane];

    float a_attn[4];
    #pragma unroll
    for (int t = 0; t < 4; ++t) a_attn[t] = Wattn[t * 16 + lr];

    char* wbase = hl + wv * 32768;             // this wave's 32 KB
    const int swz = (lr & 7) << 4;

    union AB { short8v v; __hip_bfloat162 h2[4]; };

    // issue 16 row-DMAs for tile t into buffer dst (1 KB per instr = 1 row)
    auto ISSUE = [&](int t, char* dst) {
        const int rb = t * 32 + wv * 16;
        #pragma unroll
        for (int i = 0; i < 16; ++i) {
            const int rg = min(rb + i, n_rows - 1);
            const int sslot = lane ^ (i & 7);          // pre-swizzled source slot
            gload_lds16(h + (size_t)rg * IN_DIM + sslot * 4, dst + i * 1024);
        }
    };

    if (bid < gemmtiles) {
        // prologue: fill both buffers
        ISSUE(bid, wbase);
        ISSUE(min(bid + G, gemmtiles - 1), wbase + 16384);
        __builtin_amdgcn_sched_barrier(0);

        int cur = 0;
        for (int t = bid; t < gemmtiles; t += G) {
            // drain everything except the most recently issued 16 DMAs
            asm volatile("s_waitcnt vmcnt(16)" ::: "memory");
            __builtin_amdgcn_sched_barrier(0);

            const char* rbase = wbase + cur * 16384 + lr * 1024;

            f32x4 acc[4];
            #pragma unroll
            for (int tt = 0; tt < 4; ++tt) acc[tt] = (f32x4){0.f, 0.f, 0.f, 0.f};

            #pragma unroll
            for (int ks = 0; ks < 8; ++ks) {
                const int lb = ks * 128 + lg * 32;
                const float4 x0 = *(const float4*)(rbase + (lb ^ swz));
                const float4 x1 = *(const float4*)(rbase + ((lb + 16) ^ swz));
                AB u;
                u.h2[0] = __float22bfloat162_rn(float2{x0.x, x0.y});
                u.h2[1] = __float22bfloat162_rn(float2{x0.z, x0.w});
                u.h2[2] = __float22bfloat162_rn(float2{x1.x, x1.y});
                u.h2[3] = __float22bfloat162_rn(float2{x1.z, x1.w});
                #pragma unroll
                for (int tt = 0; tt < 4; ++tt)
                    acc[tt] = __builtin_amdgcn_mfma_f32_16x16x32_bf16(u.v, Bf[ks][tt], acc[tt], 0, 0, 0);
            }

            // epilogue: C/D layout col = lane&15, row = wv*16 + lg*4 + j
            #pragma unroll
            for (int j = 0; j < 4; ++j) {
                const int row = t * 32 + wv * 16 + lg * 4 + j;
                const bool ok = row < n_rows;
                float sv = 0.0f;
                #pragma unroll
                for (int tt = 0; tt < 4; ++tt) {
                    const float v = acc[tt][j];
                    if (ok) z[(size_t)row * OUT_DIM + tt * 16 + lr] =
                        __bfloat16_as_ushort(__float2bfloat16(v));
                    sv = fmaf(v, a_attn[tt], sv);
                }
                #pragma unroll
                for (int o = 1; o < 16; o <<= 1) sv += __shfl_xor(sv, o);
                if (ok && lr == 0) s[row] = sv;
            }
            __builtin_amdgcn_sched_barrier(0);

            // refill the buffer just consumed with tile t+2G (clamped dummy at tail)
            ISSUE(min(t + 2 * G, gemmtiles - 1), wbase + cur * 16384);
            __builtin_amdgcn_sched_barrier(0);
            cur ^= 1;
        }
    }

    // drain all outstanding DMAs before reusing LDS for scatter tables
    asm volatile("s_waitcnt vmcnt(0)" ::: "memory");
    __builtin_amdgcn_sched_barrier(0);
    __syncthreads();

    // ---- scatter chunks (grid-stride) ----
    int* lcnt = (int*)hl;
    int* lwoff = lcnt + MAXNB;
    for (int c = bid; c < nchunks; c += G) {
        const int i0 = c << CHUNK_LOG2;
        const int i1 = min(i0 + (1 << CHUNK_LOG2), n_edges);
        const bool full = (i1 - i0) == (1 << CHUNK_LOG2);

        for (int j = tid; j < nb; j += 128) lcnt[j] = 0;
        __syncthreads();

        if (full) {
            const int4* dp = (const int4*)edst + (i0 >> 2);
            for (int q = tid; q < (1 << (CHUNK_LOG2 - 2)); q += 128) {
                const int4 d = dp[q];
                atomicAdd(&lcnt[d.x >> BK_LOG2], 1);
                atomicAdd(&lcnt[d.y >> BK_LOG2], 1);
                atomicAdd(&lcnt[d.z >> BK_LOG2], 1);
                atomicAdd(&lcnt[d.w >> BK_LOG2], 1);
            }
        } else {
            for (int i = i0 + tid; i < i1; i += 128)
                atomicAdd(&lcnt[edst[i] >> BK_LOG2], 1);
        }
        __syncthreads();
        for (int j = tid; j < nb; j += 128) {
            const int cv = lcnt[j];
            lwoff[j] = cv ? (j * BCAP + atomicAdd(bres + j, cv)) : 0;
        }
        __syncthreads();
        if (full) {
            const int4* dp = (const int4*)edst + (i0 >> 2);
            const int4* sp = (const int4*)esrc + (i0 >> 2);
            for (int q = tid; q < (1 << (CHUNK_LOG2 - 2)); q += 128) {
                const int4 d = dp[q];
                const int4 sv4 = sp[q];
                #define EMIT(dd, ss) { \
                    const int pos = atomicAdd(&lwoff[(dd) >> BK_LOG2], 1); \
                    brec[pos] = (ss) | (((dd) & ((1 << BK_LOG2) - 1)) << 17); }
                EMIT(d.x, sv4.x)
                EMIT(d.y, sv4.y)
                EMIT(d.z, sv4.z)
                EMIT(d.w, sv4.w)
                #undef EMIT
            }
        } else {
            for (int i = i0 + tid; i < i1; i += 128) {
                const int d = edst[i];
                const int pos = atomicAdd(&lwoff[d >> BK_LOG2], 1);
                brec[pos] = esrc[i] | ((d & ((1 << BK_LOG2) - 1)) << 17);
            }
        }
        __syncthreads();
    }
}

// per-bucket fine sort, in place: stage bucket in LDS, 128-bin count+scan,
// scatter back sorted; write (start,len) per dst. 512 threads.
__global__ __launch_bounds__(512) void p2_kernel(
    const int* __restrict__ bres, int* __restrict__ brec,
    int2* __restrict__ oln, int n_pnodes)
{
    __shared__ int srec[BCAP];          // 24 KB
    __shared__ int lh[128], lsc[128], lwf[128];
    const int b = blockIdx.x;
    const int tid = threadIdx.x;
    const int base = b * BCAP;
    const int len = min(bres[b], BCAP);

    if (tid < 128) lh[tid] = 0;
    __syncthreads();
    for (int i = tid; i < len; i += 512) {
        const int r = brec[base + i];
        srec[i] = r;
        atomicAdd(&lh[r >> 17], 1);
    }
    __syncthreads();
    if (tid < 128) lsc[tid] = lh[tid];
    __syncthreads();
    for (int d = 1; d < 128; d <<= 1) {
        int v = 0;
        if (tid < 128 && tid >= d) v = lsc[tid - d];
        __syncthreads();
        if (tid < 128) lsc[tid] += v;
        __syncthreads();
    }
    const int d0 = b << BK_LOG2;
    if (tid < 128) {
        const int st = lsc[tid] - lh[tid];   // exclusive within bucket
        lwf[tid] = st;
        if (d0 + tid < n_pnodes)
            oln[d0 + tid] = make_int2(base + st, lh[tid]);
    }
    __syncthreads();
    for (int i = tid; i < len; i += 512) {
        const int r = srec[i];
        const int pos = atomicAdd(&lwf[r >> 17], 1);
        brec[base + pos] = r & 0x1FFFF;      // in place: all reads staged
    }
}

// one wave per pnode: softmax + weighted z-sum over its sorted segment
__global__ __launch_bounds__(256) void segment_kernel(
    const int2* __restrict__ oln, const int* __restrict__ ssrc,
    const float* __restrict__ s, const unsigned short* __restrict__ z,
    float* __restrict__ out, int n_pnodes)
{
    const int p = blockIdx.x * 4 + (threadIdx.x >> 6);
    if (p >= n_pnodes) return;
    const int lane = threadIdx.x & 63;
    const int2 ol = oln[p];
    const int beg = ol.x;
    const int len = ol.y;
    const int end = beg + len;

    if (len == 0) {
        out[(size_t)p * OUT_DIM + lane] = 0.0f;
        return;
    }

    float acc = 0.0f, dsum = 0.0f;

    #define GATH1(tt, wsrc, ssrcv) { \
        float wt = __shfl(wsrc, tt); \
        int st = __shfl(ssrcv, tt); \
        acc = fmaf(wt, bf2f(z[(size_t)st * OUT_DIM + lane]), acc); }
    #define GATH8(tt, wsrc, ssrcv) { \
        float w0 = __shfl(wsrc, tt),     w1 = __shfl(wsrc, tt + 1); \
        float w2 = __shfl(wsrc, tt + 2), w3 = __shfl(wsrc, tt + 3); \
        float w4 = __shfl(wsrc, tt + 4), w5 = __shfl(wsrc, tt + 5); \
        float w6 = __shfl(wsrc, tt + 6), w7 = __shfl(wsrc, tt + 7); \
        int a0 = __shfl(ssrcv, tt),     a1 = __shfl(ssrcv, tt + 1); \
        int a2 = __shfl(ssrcv, tt + 2), a3 = __shfl(ssrcv, tt + 3); \
        int a4 = __shfl(ssrcv, tt + 4), a5 = __shfl(ssrcv, tt + 5); \
        int a6 = __shfl(ssrcv, tt + 6), a7 = __shfl(ssrcv, tt + 7); \
        float z0 = bf2f(z[(size_t)a0 * OUT_DIM + lane]); \
        float z1 = bf2f(z[(size_t)a1 * OUT_DIM + lane]); \
        float z2 = bf2f(z[(size_t)a2 * OUT_DIM + lane]); \
        float z3 = bf2f(z[(size_t)a3 * OUT_DIM + lane]); \
        float z4 = bf2f(z[(size_t)a4 * OUT_DIM + lane]); \
        float z5 = bf2f(z[(size_t)a5 * OUT_DIM + lane]); \
        float z6 = bf2f(z[(size_t)a6 * OUT_DIM + lane]); \
        float z7 = bf2f(z[(size_t)a7 * OUT_DIM + lane]); \
        acc = fmaf(w0, z0, acc); acc = fmaf(w1, z1, acc); \
        acc = fmaf(w2, z2, acc); acc = fmaf(w3, z3, acc); \
        acc = fmaf(w4, z4, acc); acc = fmaf(w5, z5, acc); \
        acc = fmaf(w6, z6, acc); acc = fmaf(w7, z7, acc); }

    if (len <= 64) {
        const bool v = lane < len;
        const int j = beg + (v ? lane : 0);
        const int sr = ssrc[j];
        const float e = v ? edge_score(s[sr]) : -INFINITY;
        float m = e;
        #pragma unroll
        for (int o = 32; o > 0; o >>= 1) m = fmaxf(m, __shfl_xor(m, o));
        float w = v ? __expf(e - m) : 0.0f;
        dsum = w;
        #pragma unroll
        for (int o = 32; o > 0; o >>= 1) dsum += __shfl_xor(dsum, o);

        int t = 0;
        for (; t + 8 <= len; t += 8) GATH8(t, w, sr)
        for (; t < len; ++t) GATH1(t, w, sr)
    } else {
        float m = -INFINITY;
        for (int j = beg + lane; j < end; j += 64)
            m = fmaxf(m, edge_score(s[ssrc[j]]));
        #pragma unroll
        for (int o = 32; o > 0; o >>= 1) m = fmaxf(m, __shfl_xor(m, o));

        for (int c = beg; c < end; c += 64) {
            const int j = c + lane;
            float w = 0.0f;
            int sr = 0;
            if (j < end) {
                sr = ssrc[j];
                w = __expf(edge_score(s[sr]) - m);
            }
            dsum += w;
            const int cn = min(64, end - c);
            int t = 0;
            for (; t + 8 <= cn; t += 8) GATH8(t, w, sr)
            for (; t < cn; ++t) GATH1(t, w, sr)
        }
        #pragma unroll
        for (int o = 32; o > 0; o >>= 1) dsum += __shfl_xor(dsum, o);
    }
    #undef GATH8
    #undef GATH1

    out[(size_t)p * OUT_DIM + lane] = acc / fmaxf(dsum, 1e-20f);
}

extern "C" void kernel_launch(void* const* d_in, const int* in_sizes, int n_in,
                              void* d_out, int out_size, void* d_ws, size_t ws_size,
                              hipStream_t stream)
{
    const float* h     = (const float*)d_in[0];
    const int*   esrc  = (const int*)d_in[1];
    const int*   edst  = (const int*)d_in[2];
    const float* Wfc   = (const float*)d_in[4];
    const float* Wattn = (const float*)d_in[5];
    float* out = (float*)d_out;

    const int n_w = in_sizes[0] / IN_DIM;   // 100000
    const int n_e = in_sizes[1];            // 1600000
    const int n_p = out_size / OUT_DIM;     // 50000
    const int nb  = (n_p + (1 << BK_LOG2) - 1) >> BK_LOG2;   // 391 coarse buckets

    // workspace layout (wtf first: 16B aligned)
    short8v* wtf            = (short8v*)d_ws;                          // 2048 frags (32 KB)
    unsigned short* z       = (unsigned short*)(wtf + 2048);           // n_w*64 bf16 bits
    float* s                = (float*)(z + (size_t)n_w * OUT_DIM);     // n_w
    int* brec               = (int*)(s + n_w);                         // nb * BCAP (padded buckets)
    int2* oln               = (int2*)(brec + (size_t)nb * BCAP);       // n_p (start,len)
    int* bres               = (int*)(oln + n_p);                       // nb

    prep_kernel<<<8, 256, 0, stream>>>(Wfc, wtf, bres, nb);

    const int nchunks = (n_e + (1 << CHUNK_LOG2) - 1) >> CHUNK_LOG2;   // 391
    const int gemmtiles = (n_w + 31) / 32;                             // 3125
    mega_kernel<<<PERSIST, 128, 0, stream>>>(h, wtf, Wattn, esrc, edst,
                                             z, s, bres, brec,
                                             n_w, n_e, nb, nchunks, gemmtiles);
    p2_kernel<<<nb, 512, 0, stream>>>(bres, brec, oln, n_p);
    segment_kernel<<<(n_p + 3) / 4, 256, 0, stream>>>(oln, brec, s, z, out, n_p);
}

// Round 22
// 97.746 us; speedup vs baseline: 1.1283x; 1.1283x over previous
//
#include <hip/hip_runtime.h>
#include <hip/hip_bf16.h>
#include <math.h>

#define IN_DIM 256
#define OUT_DIM 64
#define CHUNK_LOG2 12          // 4096 edges per scatter chunk
#define BK_LOG2 7              // 128 dsts per coarse bucket
#define MAXNB 512              // max coarse buckets (n_p <= 65536)
#define BCAP 6144              // fixed bucket capacity (mean 4096, sd 64 -> 32 sigma)

typedef __attribute__((ext_vector_type(8))) short short8v;   // 8 bf16 (4 VGPRs)
typedef __attribute__((ext_vector_type(4))) float f32x4;     // MFMA acc

__device__ __forceinline__ unsigned short f2bf(float f) {
    unsigned u = __float_as_uint(f);
    unsigned r = (u + 0x7fffu + ((u >> 16) & 1u)) >> 16;     // RTNE
    return (unsigned short)r;
}

__device__ __forceinline__ float bf2f(unsigned short b) {
    return __uint_as_float(((unsigned)b) << 16);
}

__device__ __forceinline__ float edge_score(float x) {
    float e = x > 0.0f ? x : 0.01f * x;   // leaky_relu, slope 0.01
    if (e == 0.0f) e = -1000.0f;          // where(e==0, -1000, e)
    return e;
}

// async global->LDS DMA, 16B per lane; LDS dest is wave-uniform base + lane*16
__device__ __forceinline__ void gload_lds16(const void* g, void* l) {
    __builtin_amdgcn_global_load_lds(
        (const __attribute__((address_space(1))) unsigned int*)g,
        (__attribute__((address_space(3))) unsigned int*)l, 16, 0, 0);
}

// Pre-pack W_fc (256x64 f32) into MFMA B-fragments, bf16. Grid: 8 x 256.
// Block 0 additionally zeroes bres (replaces a separate memset dispatch).
__global__ __launch_bounds__(256) void prep_kernel(
    const float* __restrict__ Wfc, short8v* __restrict__ wtf,
    int* __restrict__ bres, int nb)
{
    if (blockIdx.x == 0)
        for (int j = threadIdx.x; j < nb; j += 256) bres[j] = 0;

    const int v = blockIdx.x * 256 + threadIdx.x;   // 0..2047
    const int ks = v >> 8;
    const int t = (v >> 6) & 3;
    const int lane = v & 63;
    const int lg = lane >> 4, lr = lane & 15;
    short8v b;
    #pragma unroll
    for (int j = 0; j < 8; ++j) {
        const int k = ks * 32 + lg * 8 + j;
        b[j] = (short)f2bf(Wfc[k * OUT_DIM + t * 16 + lr]);
    }
    wtf[v] = b;
}

// MEGA kernel with INTERLEAVED roles: every 5th block (bid%5==4, plus the
// last block) runs the edge scatter; the rest run the wave-private DMA gemm.
// Scatter blocks stay co-resident with gemm blocks for the whole kernel,
// filling the gemm's DMA-latency bubbles with VALU/LDS-atomic work.
__global__ __launch_bounds__(256, 2) void mega_kernel(
    const float* __restrict__ h, const short8v* __restrict__ wtf,
    const float* __restrict__ Wattn, const int* __restrict__ esrc,
    const int* __restrict__ edst, unsigned short* __restrict__ z,
    float* __restrict__ s, int* __restrict__ bres, int* __restrict__ brec,
    int n_rows, int n_edges, int nb, int nchunks, int ntotal)
{
    __shared__ float hl[64 * IN_DIM];   // 64 KB (per-wave 16KB quarters / tables)
    const int bid = blockIdx.x;
    const int tid = threadIdx.x;

    const bool isScatter = (bid % 5 == 4) || (bid == ntotal - 1);

    if (isScatter) {
        // ---------------- scatter path ----------------
        const int c = (bid == ntotal - 1) ? (nchunks - 1) : (bid / 5);
        if (c >= nchunks) return;
        int* lcnt = (int*)hl;
        int* lwoff = lcnt + MAXNB;
        const int i0 = c << CHUNK_LOG2;
        const int i1 = min(i0 + (1 << CHUNK_LOG2), n_edges);
        const bool full = (i1 - i0) == (1 << CHUNK_LOG2);

        int4 s4[4], d4[4];
        if (full) {
            const int4* sp = (const int4*)esrc + (i0 >> 2);
            const int4* dp = (const int4*)edst + (i0 >> 2);
            #pragma unroll
            for (int j = 0; j < 4; ++j) {
                s4[j] = sp[j * 256 + tid];
                d4[j] = dp[j * 256 + tid];
            }
        }

        for (int j = tid; j < nb; j += 256) lcnt[j] = 0;
        __syncthreads();
        if (full) {
            #pragma unroll
            for (int j = 0; j < 4; ++j) {
                atomicAdd(&lcnt[d4[j].x >> BK_LOG2], 1);
                atomicAdd(&lcnt[d4[j].y >> BK_LOG2], 1);
                atomicAdd(&lcnt[d4[j].z >> BK_LOG2], 1);
                atomicAdd(&lcnt[d4[j].w >> BK_LOG2], 1);
            }
        } else {
            for (int i = i0 + tid; i < i1; i += 256)
                atomicAdd(&lcnt[edst[i] >> BK_LOG2], 1);
        }
        __syncthreads();
        for (int j = tid; j < nb; j += 256) {
            const int cv = lcnt[j];
            lwoff[j] = cv ? (j * BCAP + atomicAdd(bres + j, cv)) : 0;
        }
        __syncthreads();
        if (full) {
            #pragma unroll
            for (int j = 0; j < 4; ++j) {
                #define EMIT(dd, ss) { \
                    const int pos = atomicAdd(&lwoff[(dd) >> BK_LOG2], 1); \
                    brec[pos] = (ss) | (((dd) & ((1 << BK_LOG2) - 1)) << 17); }
                EMIT(d4[j].x, s4[j].x)
                EMIT(d4[j].y, s4[j].y)
                EMIT(d4[j].z, s4[j].z)
                EMIT(d4[j].w, s4[j].w)
                #undef EMIT
            }
        } else {
            for (int i = i0 + tid; i < i1; i += 256) {
                const int d = edst[i];
                const int pos = atomicAdd(&lwoff[d >> BK_LOG2], 1);
                brec[pos] = esrc[i] | ((d & ((1 << BK_LOG2) - 1)) << 17);
            }
        }
        return;
    }

    // -------- gemm path (wave-private, barrier-free, K-split pipeline) --------
    const int gb = bid - (bid + 1) / 5;      // skip scatter blocks
    const int lane = tid & 63;
    const int wv = tid >> 6;
    const int lg = lane >> 4;
    const int lr = lane & 15;
    const int row0 = gb * 64;

    // quarter layout: qbase + h*8KB + rowlocal*512B (+ swizzled 16B slot)
    char* qbase = (char*)hl + wv * 16384;

    // 1) B fragments + attn weights FIRST (oldest in vmcnt order, L2-hot)
    short8v Bf[8][4];
    #pragma unroll
    for (int ks = 0; ks < 8; ++ks)
        #pragma unroll
        for (int t = 0; t < 4; ++t)
            Bf[ks][t] = wtf[(ks * 4 + t) * 64 + lane];

    float a_attn[4];
    #pragma unroll
    for (int t = 0; t < 4; ++t) a_attn[t] = Wattn[t * 16 + lr];

    // 2) DMA half0 then half1: 2 rows per instr (1KB contiguous dest).
    const int rl_dma = (lane >> 5);          // 0 or 1 within the pair
    const int slot = lane & 31;
    #pragma unroll
    for (int hh = 0; hh < 2; ++hh) {
        #pragma unroll
        for (int j = 0; j < 8; ++j) {
            const int rl = wv * 16 + 2 * j + rl_dma;
            const int rg = min(row0 + rl, n_rows - 1);
            const int sslot = slot ^ (rl & 7);
            gload_lds16(h + (size_t)rg * IN_DIM + hh * 128 + sslot * 4,
                        qbase + hh * 8192 + j * 1024);
        }
        if (hh == 0) __builtin_amdgcn_sched_barrier(0);  // pin half0 before half1
    }
    __builtin_amdgcn_sched_barrier(0);

    // 3) wait Bf + half0; half1 stays in flight
    asm volatile("s_waitcnt vmcnt(8)" ::: "memory");
    __builtin_amdgcn_sched_barrier(0);

    f32x4 acc[4];
    #pragma unroll
    for (int t = 0; t < 4; ++t) acc[t] = (f32x4){0.f, 0.f, 0.f, 0.f};

    const char* rbase = qbase + lr * 512;
    const int swz = (lr & 7) << 4;

    union AB { short8v v; __hip_bfloat162 h2[4]; };
    #pragma unroll
    for (int ks = 0; ks < 4; ++ks) {
        const int lb = ks * 128 + lg * 32;       // byte offset within half-row
        const float4 x0 = *(const float4*)(rbase + (lb ^ swz));
        const float4 x1 = *(const float4*)(rbase + ((lb + 16) ^ swz));
        AB u;
        u.h2[0] = __float22bfloat162_rn(float2{x0.x, x0.y});
        u.h2[1] = __float22bfloat162_rn(float2{x0.z, x0.w});
        u.h2[2] = __float22bfloat162_rn(float2{x1.x, x1.y});
        u.h2[3] = __float22bfloat162_rn(float2{x1.z, x1.w});
        #pragma unroll
        for (int t = 0; t < 4; ++t)
            acc[t] = __builtin_amdgcn_mfma_f32_16x16x32_bf16(u.v, Bf[ks][t], acc[t], 0, 0, 0);
    }

    // 4) drain half1, compute ks4..7
    asm volatile("s_waitcnt vmcnt(0)" ::: "memory");
    __builtin_amdgcn_sched_barrier(0);

    #pragma unroll
    for (int ks = 4; ks < 8; ++ks) {
        const int lb = (ks - 4) * 128 + lg * 32;
        const char* rb1 = rbase + 8192;
        const float4 x0 = *(const float4*)(rb1 + (lb ^ swz));
        const float4 x1 = *(const float4*)(rb1 + ((lb + 16) ^ swz));
        AB u;
        u.h2[0] = __float22bfloat162_rn(float2{x0.x, x0.y});
        u.h2[1] = __float22bfloat162_rn(float2{x0.z, x0.w});
        u.h2[2] = __float22bfloat162_rn(float2{x1.x, x1.y});
        u.h2[3] = __float22bfloat162_rn(float2{x1.z, x1.w});
        #pragma unroll
        for (int t = 0; t < 4; ++t)
            acc[t] = __builtin_amdgcn_mfma_f32_16x16x32_bf16(u.v, Bf[ks][t], acc[t], 0, 0, 0);
    }

    // epilogue: C/D layout col = lane&15, row = wv*16 + lg*4 + j
    #pragma unroll
    for (int j = 0; j < 4; ++j) {
        const int row = row0 + wv * 16 + lg * 4 + j;
        const bool ok = row < n_rows;
        float sv = 0.0f;
        #pragma unroll
        for (int t = 0; t < 4; ++t) {
            const float v = acc[t][j];
            if (ok) z[(size_t)row * OUT_DIM + t * 16 + lr] =
                __bfloat16_as_ushort(__float2bfloat16(v));
            sv = fmaf(v, a_attn[t], sv);
        }
        #pragma unroll
        for (int o = 1; o < 16; o <<= 1) sv += __shfl_xor(sv, o);
        if (ok && lr == 0) s[row] = sv;
    }
}

// per-bucket fine sort, in place: stage bucket in LDS, 128-bin count+scan,
// scatter back sorted; write (start,len) per dst. 512 threads.
__global__ __launch_bounds__(512) void p2_kernel(
    const int* __restrict__ bres, int* __restrict__ brec,
    int2* __restrict__ oln, int n_pnodes)
{
    __shared__ int srec[BCAP];          // 24 KB
    __shared__ int lh[128], lsc[128], lwf[128];
    const int b = blockIdx.x;
    const int tid = threadIdx.x;
    const int base = b * BCAP;
    const int len = min(bres[b], BCAP);

    if (tid < 128) lh[tid] = 0;
    __syncthreads();
    for (int i = tid; i < len; i += 512) {
        const int r = brec[base + i];
        srec[i] = r;
        atomicAdd(&lh[r >> 17], 1);
    }
    __syncthreads();
    if (tid < 128) lsc[tid] = lh[tid];
    __syncthreads();
    for (int d = 1; d < 128; d <<= 1) {
        int v = 0;
        if (tid < 128 && tid >= d) v = lsc[tid - d];
        __syncthreads();
        if (tid < 128) lsc[tid] += v;
        __syncthreads();
    }
    const int d0 = b << BK_LOG2;
    if (tid < 128) {
        const int st = lsc[tid] - lh[tid];   // exclusive within bucket
        lwf[tid] = st;
        if (d0 + tid < n_pnodes)
            oln[d0 + tid] = make_int2(base + st, lh[tid]);
    }
    __syncthreads();
    for (int i = tid; i < len; i += 512) {
        const int r = srec[i];
        const int pos = atomicAdd(&lwf[r >> 17], 1);
        brec[base + pos] = r & 0x1FFFF;      // in place: all reads staged
    }
}

// one wave per pnode: softmax + weighted z-sum over its sorted segment
__global__ __launch_bounds__(256) void segment_kernel(
    const int2* __restrict__ oln, const int* __restrict__ ssrc,
    const float* __restrict__ s, const unsigned short* __restrict__ z,
    float* __restrict__ out, int n_pnodes)
{
    const int p = blockIdx.x * 4 + (threadIdx.x >> 6);
    if (p >= n_pnodes) return;
    const int lane = threadIdx.x & 63;
    const int2 ol = oln[p];
    const int beg = ol.x;
    const int len = ol.y;
    const int end = beg + len;

    if (len == 0) {
        out[(size_t)p * OUT_DIM + lane] = 0.0f;
        return;
    }

    float acc = 0.0f, dsum = 0.0f;

    #define GATH1(tt, wsrc, ssrcv) { \
        float wt = __shfl(wsrc, tt); \
        int st = __shfl(ssrcv, tt); \
        acc = fmaf(wt, bf2f(z[(size_t)st * OUT_DIM + lane]), acc); }
    #define GATH8(tt, wsrc, ssrcv) { \
        float w0 = __shfl(wsrc, tt),     w1 = __shfl(wsrc, tt + 1); \
        float w2 = __shfl(wsrc, tt + 2), w3 = __shfl(wsrc, tt + 3); \
        float w4 = __shfl(wsrc, tt + 4), w5 = __shfl(wsrc, tt + 5); \
        float w6 = __shfl(wsrc, tt + 6), w7 = __shfl(wsrc, tt + 7); \
        int a0 = __shfl(ssrcv, tt),     a1 = __shfl(ssrcv, tt + 1); \
        int a2 = __shfl(ssrcv, tt + 2), a3 = __shfl(ssrcv, tt + 3); \
        int a4 = __shfl(ssrcv, tt + 4), a5 = __shfl(ssrcv, tt + 5); \
        int a6 = __shfl(ssrcv, tt + 6), a7 = __shfl(ssrcv, tt + 7); \
        float z0 = bf2f(z[(size_t)a0 * OUT_DIM + lane]); \
        float z1 = bf2f(z[(size_t)a1 * OUT_DIM + lane]); \
        float z2 = bf2f(z[(size_t)a2 * OUT_DIM + lane]); \
        float z3 = bf2f(z[(size_t)a3 * OUT_DIM + lane]); \
        float z4 = bf2f(z[(size_t)a4 * OUT_DIM + lane]); \
        float z5 = bf2f(z[(size_t)a5 * OUT_DIM + lane]); \
        float z6 = bf2f(z[(size_t)a6 * OUT_DIM + lane]); \
        float z7 = bf2f(z[(size_t)a7 * OUT_DIM + lane]); \
        acc = fmaf(w0, z0, acc); acc = fmaf(w1, z1, acc); \
        acc = fmaf(w2, z2, acc); acc = fmaf(w3, z3, acc); \
        acc = fmaf(w4, z4, acc); acc = fmaf(w5, z5, acc); \
        acc = fmaf(w6, z6, acc); acc = fmaf(w7, z7, acc); }

    if (len <= 64) {
        const bool v = lane < len;
        const int j = beg + (v ? lane : 0);
        const int sr = ssrc[j];
        const float e = v ? edge_score(s[sr]) : -INFINITY;
        float m = e;
        #pragma unroll
        for (int o = 32; o > 0; o >>= 1) m = fmaxf(m, __shfl_xor(m, o));
        float w = v ? __expf(e - m) : 0.0f;
        dsum = w;
        #pragma unroll
        for (int o = 32; o > 0; o >>= 1) dsum += __shfl_xor(dsum, o);

        int t = 0;
        for (; t + 8 <= len; t += 8) GATH8(t, w, sr)
        for (; t < len; ++t) GATH1(t, w, sr)
    } else {
        float m = -INFINITY;
        for (int j = beg + lane; j < end; j += 64)
            m = fmaxf(m, edge_score(s[ssrc[j]]));
        #pragma unroll
        for (int o = 32; o > 0; o >>= 1) m = fmaxf(m, __shfl_xor(m, o));

        for (int c = beg; c < end; c += 64) {
            const int j = c + lane;
            float w = 0.0f;
            int sr = 0;
            if (j < end) {
                sr = ssrc[j];
                w = __expf(edge_score(s[sr]) - m);
            }
            dsum += w;
            const int cn = min(64, end - c);
            int t = 0;
            for (; t + 8 <= cn; t += 8) GATH8(t, w, sr)
            for (; t < cn; ++t) GATH1(t, w, sr)
        }
        #pragma unroll
        for (int o = 32; o > 0; o >>= 1) dsum += __shfl_xor(dsum, o);
    }
    #undef GATH8
    #undef GATH1

    out[(size_t)p * OUT_DIM + lane] = acc / fmaxf(dsum, 1e-20f);
}

extern "C" void kernel_launch(void* const* d_in, const int* in_sizes, int n_in,
                              void* d_out, int out_size, void* d_ws, size_t ws_size,
                              hipStream_t stream)
{
    const float* h     = (const float*)d_in[0];
    const int*   esrc  = (const int*)d_in[1];
    const int*   edst  = (const int*)d_in[2];
    const float* Wfc   = (const float*)d_in[4];
    const float* Wattn = (const float*)d_in[5];
    float* out = (float*)d_out;

    const int n_w = in_sizes[0] / IN_DIM;   // 100000
    const int n_e = in_sizes[1];            // 1600000
    const int n_p = out_size / OUT_DIM;     // 50000
    const int nb  = (n_p + (1 << BK_LOG2) - 1) >> BK_LOG2;   // 391 coarse buckets

    // workspace layout (wtf first: 16B aligned)
    short8v* wtf            = (short8v*)d_ws;                          // 2048 frags (32 KB)
    unsigned short* z       = (unsigned short*)(wtf + 2048);           // n_w*64 bf16 bits
    float* s                = (float*)(z + (size_t)n_w * OUT_DIM);     // n_w
    int* brec               = (int*)(s + n_w);                         // nb * BCAP (padded buckets)
    int2* oln               = (int2*)(brec + (size_t)nb * BCAP);       // n_p (start,len)
    int* bres               = (int*)(oln + n_p);                       // nb

    prep_kernel<<<8, 256, 0, stream>>>(Wfc, wtf, bres, nb);

    const int nchunks = (n_e + (1 << CHUNK_LOG2) - 1) >> CHUNK_LOG2;   // 391
    const int gemmb = (n_w + 63) / 64;                                 // 1563
    // interleaved grid: every 5th block is a scatter block (390 of them),
    // plus the final block handles the last chunk -> 391 scatter + 1563 gemm
    const int ntotal = gemmb + nchunks;                                // 1954
    mega_kernel<<<ntotal, 256, 0, stream>>>(h, wtf, Wattn, esrc, edst,
                                            z, s, bres, brec,
                                            n_w, n_e, nb, nchunks, ntotal);
    p2_kernel<<<nb, 512, 0, stream>>>(bres, brec, oln, n_p);
    segment_kernel<<<(n_p + 3) / 4, 256, 0, stream>>>(oln, brec, s, z, out, n_p);
}